// Round 1
// baseline (195.479 us; speedup 1.0000x reference)
//
#include <hip/hip_runtime.h>
#include <stdint.h>

#define NCELL (512 * 512)
#define DIN   136

// output layout (flat f32, concat in return order)
#define OUT_LAT 2097152ull                 // N*8
#define OUT_C   35651584ull                // OUT_LAT + N*128
#define OUT_H   52428800ull                // OUT_C + N*64

// packed-weight offsets in d_ws (bf16 elements)
#define WPRE_OFF  0        // [5][64][32]   = 10240
#define W2_OFF    10240    // [4][256][32]  = 32768
#define WPOST_OFF 43008    // [2][144][32]  = 9216
#define WTOTAL    52224

typedef __bf16 bf16x8 __attribute__((ext_vector_type(8)));
typedef float  f32x4  __attribute__((ext_vector_type(4)));

__device__ __forceinline__ unsigned short f2bf(float f) {
    unsigned int u = __float_as_uint(f);
    u += 0x7FFF + ((u >> 16) & 1);          // round-to-nearest-even
    return (unsigned short)(u >> 16);
}
__device__ __forceinline__ int pack2(float a, float b) {
    return (int)f2bf(a) | ((int)f2bf(b) << 16);
}
__device__ __forceinline__ float fast_sigmoid(float x) {
    return __builtin_amdgcn_rcpf(1.f + __expf(-x));
}
__device__ __forceinline__ float fast_tanh(float x) {
    float e = __expf(2.f * x);              // inf-safe: rcp(inf)=0 -> 1; e->0 -> -1
    return 1.f - 2.f * __builtin_amdgcn_rcpf(e + 1.f);
}

// Repack weights to bf16, MFMA-B-fragment-friendly: [K/32][Ncol][32]
__global__ void prep_weights(const float* __restrict__ Wpre,
                             const float* __restrict__ Wih,
                             const float* __restrict__ Whh,
                             const float* __restrict__ Wpost,
                             unsigned short* __restrict__ ws) {
    int i = blockIdx.x * 256 + threadIdx.x;
    if (i < 10240) {                                   // Wpre' : K 136->160 pad, N=64
        int k = i & 31, n = (i >> 5) & 63, s = i >> 11;
        int K = s * 32 + k;
        ws[i] = (K < DIN) ? f2bf(Wpre[K * 64 + n]) : (unsigned short)0;
    } else if (i < 43008) {                            // W2'   : K=128 (ih||hh), N=256
        int j = i - 10240;
        int k = j & 31, n = (j >> 5) & 255, s = j >> 13;
        int K = s * 32 + k;
        float v = (K < 64) ? Wih[K * 256 + n] : Whh[(K - 64) * 256 + n];
        ws[i] = f2bf(v);
    } else if (i < WTOTAL) {                           // Wpost': K=64, N 136->144 pad
        int j = i - 43008;
        int k = j & 31;
        int t = j >> 5;
        int n = t % 144;
        int s = t / 144;
        int K = s * 32 + k;
        ws[i] = (n < DIN) ? f2bf(Wpost[K * DIN + n]) : (unsigned short)0;
    }
}

// Fused: gather -> GEMM1(tanh) -> GEMM2 -> LSTM -> GEMM3(tanh)
// block = 256 threads (4 waves) = 64 cells
__global__ __launch_bounds__(256, 4) void knet_fused(
    const float* __restrict__ dyn_in,
    const float* __restrict__ lat_prev,
    const float* __restrict__ lstm_c,
    const float* __restrict__ lstm_h,
    const int*   __restrict__ coming_from,
    const unsigned short* __restrict__ wsp,   // packed weights base
    const float* __restrict__ b_pre,
    const float* __restrict__ b_lstm,
    const float* __restrict__ b_post,
    float* __restrict__ out) {
    // Xs: [64][168] bf16 (X tile, K padded 136->160, stride 168 kills bank conflicts)
    //     reused in phase>=2 as H3 [64][64] bf16 (128B rows, XOR-swizzled)
    __shared__ __align__(16) unsigned short Xs[64 * 168];
    // A2: [64][128] bf16 (cols 0-63 = pre, 64-127 = h_prev), XOR-swizzled rows
    __shared__ __align__(16) unsigned short A2s[64 * 128];

    const int t  = threadIdx.x;
    const int p0 = blockIdx.x * 64;
    const unsigned short* wpre_p  = wsp + WPRE_OFF;
    const unsigned short* w2_p    = wsp + W2_OFF;
    const unsigned short* wpost_p = wsp + WPOST_OFF;

    // ---------------- phase 0: staging ----------------
    {
        // h_prev -> A2 cols 64..127 (bf16, swizzled). 16 values/thread.
        int r = t >> 2, q = t & 3;
        int sw = (r & 7) << 4;
        const float4* hp = (const float4*)(lstm_h + (size_t)(p0 + r) * 64 + q * 16);
        float4 v0 = hp[0], v1 = hp[1], v2 = hp[2], v3 = hp[3];
        char* rowp = (char*)A2s + r * 256;
        int4 w0{pack2(v0.x, v0.y), pack2(v0.z, v0.w), pack2(v1.x, v1.y), pack2(v1.z, v1.w)};
        int4 w1{pack2(v2.x, v2.y), pack2(v2.z, v2.w), pack2(v3.x, v3.y), pack2(v3.z, v3.w)};
        *(int4*)(rowp + ((128 + 32 * q) ^ sw))      = w0;
        *(int4*)(rowp + ((128 + 32 * q + 16) ^ sw)) = w1;

        // zero pad cols 136..167 of Xs
        int4 z{0, 0, 0, 0};
        *(int4*)((char*)Xs + r * 336 + 272 + 16 * q) = z;
    }
    if (t < 128) {  // dyn_in -> Xs cols 0..7
        int r = t >> 1, c = (t & 1) * 4;
        float4 v = *(const float4*)(dyn_in + (size_t)(p0 + r) * 8 + c);
        int2 w2v{pack2(v.x, v.y), pack2(v.z, v.w)};
        *(int2*)((char*)Xs + r * 336 + c * 2) = w2v;
    }
#pragma unroll
    for (int qq = 0; qq < 2; ++qq) {  // lat gather -> Xs cols 8..135
        int q = t + qq * 256;
        int r = q >> 3, d = q & 7;
        int src = coming_from[(size_t)d * NCELL + p0 + r];
        const float4* lp = (const float4*)(lat_prev + (size_t)src * 128 + d * 16);
        float4 v0 = lp[0], v1 = lp[1], v2 = lp[2], v3 = lp[3];
        char* dst = (char*)Xs + r * 336 + 16 + 32 * d;
        int4 w0{pack2(v0.x, v0.y), pack2(v0.z, v0.w), pack2(v1.x, v1.y), pack2(v1.z, v1.w)};
        int4 w1{pack2(v2.x, v2.y), pack2(v2.z, v2.w), pack2(v3.x, v3.y), pack2(v3.z, v3.w)};
        *(int4*)dst        = w0;
        *(int4*)(dst + 16) = w1;
    }
    __syncthreads();

    const int lane = t & 63;
    const int w    = t >> 6;     // wave id: owns N-tiles {w, w+4, ...}, M-tiles 0..3
    const int lr   = lane & 15;  // A-row / B-col / C-col within tile
    const int lg   = lane >> 4;  // k-group (A/B), row-group (C)

    // ---------------- phase 1: GEMM1 = X[64x160] @ Wpre'[160x64], tanh -> A2 cols 0..63
    {
        f32x4 acc1[4];
#pragma unroll
        for (int m = 0; m < 4; ++m) acc1[m] = (f32x4){0.f, 0.f, 0.f, 0.f};
#pragma unroll
        for (int s = 0; s < 5; ++s) {
            bf16x8 b = *(const bf16x8*)(wpre_p + ((s * 64 + w * 16 + lr) * 32 + lg * 8));
#pragma unroll
            for (int m = 0; m < 4; ++m) {
                bf16x8 a = *(const bf16x8*)((const char*)Xs + (m * 16 + lr) * 336 +
                                            (s * 32 + lg * 8) * 2);
                acc1[m] = __builtin_amdgcn_mfma_f32_16x16x32_bf16(a, b, acc1[m], 0, 0, 0);
            }
        }
        float bp = b_pre[w * 16 + lr];
        int colb = (w * 16 + lr) * 2;
#pragma unroll
        for (int m = 0; m < 4; ++m)
#pragma unroll
            for (int rr = 0; rr < 4; ++rr) {
                int row = m * 16 + lg * 4 + rr;
                float pv = fast_tanh(acc1[m][rr] + bp);
                *(unsigned short*)((char*)A2s + row * 256 + (colb ^ ((row & 7) << 4))) =
                    f2bf(pv);
            }
    }
    __syncthreads();

    // ---------------- phase 2: GEMM2 = [pre||h][64x128] @ W2'[128x256] + LSTM
    {
        f32x4 acc2[4][4];  // [m][j], gate tile n = w + 4*j  (j: 0=i,1=f,2=g,3=o)
#pragma unroll
        for (int m = 0; m < 4; ++m)
#pragma unroll
            for (int j = 0; j < 4; ++j) acc2[m][j] = (f32x4){0.f, 0.f, 0.f, 0.f};
#pragma unroll
        for (int s = 0; s < 4; ++s) {
            bf16x8 a[4];
#pragma unroll
            for (int m = 0; m < 4; ++m) {
                int row = m * 16 + lr;
                int cb  = (s * 32 + lg * 8) * 2;
                a[m] = *(const bf16x8*)((char*)A2s + row * 256 + (cb ^ ((row & 7) << 4)));
            }
#pragma unroll
            for (int j = 0; j < 4; ++j) {
                int n = w + 4 * j;
                bf16x8 b = *(const bf16x8*)(w2_p + ((s * 256 + n * 16 + lr) * 32 + lg * 8));
#pragma unroll
                for (int m = 0; m < 4; ++m)
                    acc2[m][j] =
                        __builtin_amdgcn_mfma_f32_16x16x32_bf16(a[m], b, acc2[m][j], 0, 0, 0);
            }
        }
        // LSTM pointwise: lane owns hid = w*16+lr for 16 rows
        int hid = w * 16 + lr;
        float bi = b_lstm[hid], bf = b_lstm[64 + hid];
        float bg = b_lstm[128 + hid], bo = b_lstm[192 + hid];
#pragma unroll
        for (int m = 0; m < 4; ++m)
#pragma unroll
            for (int rr = 0; rr < 4; ++rr) {
                int row = m * 16 + lg * 4 + rr;
                size_t cell = (size_t)(p0 + row);
                float iv = fast_sigmoid(acc2[m][0][rr] + bi);
                float fv = fast_sigmoid(acc2[m][1][rr] + bf);
                float gv = fast_tanh(acc2[m][2][rr] + bg);
                float ov = fast_sigmoid(acc2[m][3][rr] + bo);
                float cold = lstm_c[cell * 64 + hid];
                float cn = fv * cold + iv * gv;
                float hn = ov * fast_tanh(cn);
                out[OUT_C + cell * 64 + hid] = cn;
                out[OUT_H + cell * 64 + hid] = hn;
                // h -> H3 (aliases Xs), [64][64] bf16, 128B rows, swizzled
                *(unsigned short*)((char*)Xs + row * 128 + ((hid * 2) ^ ((row & 7) << 4))) =
                    f2bf(hn);
            }
    }
    __syncthreads();

    // ---------------- phase 3: GEMM3 = h[64x64] @ Wpost'[64x144], tanh -> dyn/lat out
    {
        f32x4 acc3[4][3];
#pragma unroll
        for (int m = 0; m < 4; ++m)
#pragma unroll
            for (int jj = 0; jj < 3; ++jj) acc3[m][jj] = (f32x4){0.f, 0.f, 0.f, 0.f};
        const int ntiles = (w == 0) ? 3 : 2;  // tiles {w, w+4, (w==0: 8)} cover 0..8
#pragma unroll
        for (int s = 0; s < 2; ++s) {
            bf16x8 a[4];
#pragma unroll
            for (int m = 0; m < 4; ++m) {
                int row = m * 16 + lr;
                int cb  = (s * 32 + lg * 8) * 2;
                a[m] = *(const bf16x8*)((char*)Xs + row * 128 + (cb ^ ((row & 7) << 4)));
            }
#pragma unroll
            for (int jj = 0; jj < 3; ++jj) {
                if (jj < ntiles) {
                    int n = w + 4 * jj;
                    bf16x8 b =
                        *(const bf16x8*)(wpost_p + ((s * 144 + n * 16 + lr) * 32 + lg * 8));
#pragma unroll
                    for (int m = 0; m < 4; ++m)
                        acc3[m][jj] = __builtin_amdgcn_mfma_f32_16x16x32_bf16(a[m], b,
                                                                              acc3[m][jj],
                                                                              0, 0, 0);
                }
            }
        }
#pragma unroll
        for (int jj = 0; jj < 3; ++jj) {
            if (jj < ntiles) {
                int n   = w + 4 * jj;
                int col = n * 16 + lr;
                if (col < DIN) {
                    float bp2 = b_post[col];
#pragma unroll
                    for (int m = 0; m < 4; ++m)
#pragma unroll
                        for (int rr = 0; rr < 4; ++rr) {
                            int row = m * 16 + lg * 4 + rr;
                            size_t cell = (size_t)(p0 + row);
                            float pv = fast_tanh(acc3[m][jj][rr] + bp2);
                            if (col < 8)
                                out[cell * 8 + col] = pv;
                            else
                                out[OUT_LAT + cell * 128 + (col - 8)] = pv;
                        }
                }
            }
        }
    }
}

extern "C" void kernel_launch(void* const* d_in, const int* in_sizes, int n_in,
                              void* d_out, int out_size, void* d_ws, size_t ws_size,
                              hipStream_t stream) {
    const float* dyn_in      = (const float*)d_in[0];
    const float* lat_prev    = (const float*)d_in[1];
    const float* lstm_c      = (const float*)d_in[2];
    const float* lstm_h      = (const float*)d_in[3];
    const int*   coming_from = (const int*)d_in[5];
    const float* W_pre  = (const float*)d_in[7];
    const float* b_pre  = (const float*)d_in[8];
    const float* W_ih   = (const float*)d_in[9];
    const float* W_hh   = (const float*)d_in[10];
    const float* b_lstm = (const float*)d_in[11];
    const float* W_post = (const float*)d_in[12];
    const float* b_post = (const float*)d_in[13];
    unsigned short* wsp = (unsigned short*)d_ws;

    prep_weights<<<(WTOTAL + 255) / 256, 256, 0, stream>>>(W_pre, W_ih, W_hh, W_post, wsp);
    knet_fused<<<NCELL / 64, 256, 0, stream>>>(dyn_in, lat_prev, lstm_c, lstm_h, coming_from,
                                               wsp, b_pre, b_lstm, b_post, (float*)d_out);
}